// Round 3
// baseline (167.746 us; speedup 1.0000x reference)
//
#include <hip/hip_runtime.h>

// RSNN: B=32, T=500, N_IN=512, N_HID=2048.
// Mathematical structure: reset = (mem > -55). Once ALL neurons of a batch
// have mem > -55 at the top of a step, mem = base*(1-reset) = 0 for all, and
// mem==0 > -55 is absorbing (the matmuls are multiplied by exactly 0.0
// forever). From that step (te) on, the output is a closed-form refractory
// state machine: neuron spikes at s = t-te with (s >= s0) && (s % 5 == s0),
// s0 = max(refrac_at_te - 1, 0).
//
// Kernel 1 (scan): faithful recurrence + per-step block vote; exits when the
//   vote proves absorption (t=0 on the benchmark data). Verified absmax=0 (R1).
// Kernel 2 (expand): closed-form pattern write of the 131 MB output.
//   Deep per-thread streaming: 20 timesteps (320 B) per thread, state loaded
//   once, nontemporal native-vector stores -> HBM-write-bound.

#define T_STEPS   500
#define BATCH     32
#define N_INP     512
#define N_HID     2048
#define THRESH    (-55.0f)
#define BETA_V    0.95f
#define REST      70.0f
#define REFRAC_P  5

#define T_PER_THREAD 20
#define T_GROUPS     (T_STEPS / T_PER_THREAD)       // 25
#define QUADS        (BATCH * N_HID / 4)            // 16384 = 2^14

typedef float vfloat4 __attribute__((ext_vector_type(4)));  // native vec for nontemporal builtin

__global__ __launch_bounds__(1024) void rsnn_scan(
    const float* __restrict__ x,       // [B, T, N_INP]
    const float* __restrict__ mem0,    // [B, N_HID]
    const float* __restrict__ W_in,    // [N_HID, N_INP]
    const float* __restrict__ b_in,    // [N_HID]
    const float* __restrict__ W_rec,   // [N_HID, N_HID]
    const float* __restrict__ b_rec,   // [N_HID]
    float* __restrict__ out,           // [T, B, N_HID]
    int* __restrict__ tEntry,          // [B]
    unsigned char* __restrict__ refracOut) // [B, N_HID]
{
    const int b   = blockIdx.x;
    const int tid = threadIdx.x;
    const int hh[2] = { tid, tid + 1024 };

    __shared__ float spkLDS[N_HID];
    __shared__ int   flag;

    float mem[2];
    int   rr[2] = { 0, 0 };
    float spk[2] = { 0.f, 0.f };

#pragma unroll
    for (int j = 0; j < 2; ++j) mem[j] = mem0[b * N_HID + hh[j]];
#pragma unroll
    for (int j = 0; j < 2; ++j) spkLDS[hh[j]] = 0.f;

    int te = T_STEPS;

    for (int t = 0; t < T_STEPS; ++t) {
        if (tid == 0) flag = 0;
        __syncthreads();
        if (!(mem[0] > THRESH) || !(mem[1] > THRESH)) flag = 1;
        __syncthreads();
        if (flag == 0) { te = t; break; }  // block-uniform: absorbing fast mode

        // ---- general (slow) step — never executed on benchmark data ----
#pragma unroll
        for (int j = 0; j < 2; ++j) {
            const int h = hh[j];
            rr[j] = max(rr[j] - 1, 0);
            const bool reset = (mem[j] > THRESH);
            float m;
            if (!reset) {
                float rec = 0.f;
                const float* wr = W_rec + (size_t)h * N_HID;
                for (int k = 0; k < N_HID; ++k) rec += spkLDS[k] * wr[k];
                float cur = b_in[h];
                const float* xi = x + ((size_t)b * T_STEPS + t) * N_INP;
                const float* wi = W_in + (size_t)h * N_INP;
                for (int k = 0; k < N_INP; ++k) cur += xi[k] * wi[k];
                m = BETA_V * (mem[j] + REST) + cur + rec + b_rec[h] - REST;
            } else {
                m = 0.f;
            }
            mem[j] = m;
            spk[j] = ((mem[j] > THRESH) && (rr[j] == 0)) ? 1.f : 0.f;
            if (spk[j] > 0.f) rr[j] = REFRAC_P;
            out[(size_t)t * (BATCH * N_HID) + (size_t)b * N_HID + h] = spk[j];
        }
        __syncthreads();  // finish spkLDS reads before overwrite
#pragma unroll
        for (int j = 0; j < 2; ++j) spkLDS[hh[j]] = spk[j];
        // next iteration's vote barrier orders these writes before reads
    }

#pragma unroll
    for (int j = 0; j < 2; ++j)
        refracOut[b * N_HID + hh[j]] = (unsigned char)rr[j];
    if (tid == 0) tEntry[b] = te;
}

// Each thread owns one (b, h quad) column and streams T_PER_THREAD timesteps.
// State (tEntry, refrac) loaded once; phase arithmetic incremental; stores
// nontemporal (output >> L2).
__global__ __launch_bounds__(256) void rsnn_expand(
    float* __restrict__ out,
    const int* __restrict__ tEntry,
    const unsigned char* __restrict__ refrac)
{
    const unsigned u  = blockIdx.x * 256u + threadIdx.x;   // [0, 409600)
    const unsigned q  = u & (QUADS - 1);                   // (b, h/4)
    const unsigned tg = u >> 14;                           // t-group [0, 25)

    const int b  = (int)(q >> 9);                          // q / (N_HID/4)
    const int h  = (int)((q & 511u) << 2);                 // quad base within row

    const int te = tEntry[b];
    const uchar4 R = *(const uchar4*)(refrac + b * N_HID + h);
    const int s0x = R.x ? (int)R.x - 1 : 0;
    const int s0y = R.y ? (int)R.y - 1 : 0;
    const int s0z = R.z ? (int)R.z - 1 : 0;
    const int s0w = R.w ? (int)R.w - 1 : 0;

    const int t0 = (int)tg * T_PER_THREAD;
    // initial s and phase for k=0 (may be in the pre-entry region)
    int s  = t0 - te;
    int sm;
    {   // s % 5 for possibly-negative s (only the s>=0 values are ever used)
        int ss = s >= 0 ? s : 0;
        sm = ss - (ss / 5) * 5;
        if (s < 0) sm = -1;  // flag: recompute once s becomes >= 0
    }

    float* p = out + ((size_t)t0 * (BATCH * N_HID)) + (size_t)b * N_HID + h;

#pragma unroll
    for (int k = 0; k < T_PER_THREAD; ++k) {
        if (s >= 0) {                       // t >= te: fast-mode region
            if (sm < 0) sm = 0;             // s just reached 0
            vfloat4 o;
            o.x = (sm == s0x && s >= s0x) ? 1.f : 0.f;
            o.y = (sm == s0y && s >= s0y) ? 1.f : 0.f;
            o.z = (sm == s0z && s >= s0z) ? 1.f : 0.f;
            o.w = (sm == s0w && s >= s0w) ? 1.f : 0.f;
            __builtin_nontemporal_store(o, (vfloat4*)p);
            sm = (sm == 4) ? 0 : sm + 1;
        }
        ++s;
        p += BATCH * N_HID;
    }
}

extern "C" void kernel_launch(void* const* d_in, const int* in_sizes, int n_in,
                              void* d_out, int out_size, void* d_ws, size_t ws_size,
                              hipStream_t stream) {
    const float* x     = (const float*)d_in[0];
    const float* mem0  = (const float*)d_in[1];
    const float* W_in  = (const float*)d_in[2];
    const float* b_in  = (const float*)d_in[3];
    const float* W_rec = (const float*)d_in[4];
    const float* b_rec = (const float*)d_in[5];
    float* out = (float*)d_out;

    int* tEntry = (int*)d_ws;                                   // 32 ints
    unsigned char* refrac = (unsigned char*)d_ws + 128;         // B*N_HID bytes

    rsnn_scan<<<BATCH, 1024, 0, stream>>>(x, mem0, W_in, b_in, W_rec, b_rec,
                                          out, tEntry, refrac);

    const unsigned threads = T_GROUPS * QUADS;                  // 409,600
    rsnn_expand<<<threads / 256u, 256, 0, stream>>>(out, tEntry, refrac);
}

// Round 4
// 166.759 us; speedup vs baseline: 1.0059x; 1.0059x over previous
//
#include <hip/hip_runtime.h>

// RSNN: B=32, T=500, N_IN=512, N_HID=2048.
// Mathematical structure: reset = heaviside(mem - (-55)) = (mem > -55). Once
// ALL neurons of a batch have mem > -55 at the top of a step, mem becomes
// exactly 0 for all (mem = base*(1-reset)), and mem==0 > -55 is absorbing:
// the input/recurrent matmuls are multiplied by exactly 0.0 forever. From
// that step te on, the output is a closed-form refractory machine: with r =
// refrac at top of step te, s0 = max(r-1,0) in [0,4], neuron spikes at
// s = t-te iff s % 5 == s0 (the s>=s0 condition is implied since s0<=4).
// Verified absmax=0 on rounds 1 and 3.
//
// SINGLE fused kernel, no inter-block communication: each block serves one
// (time-chunk, batch, half-row) slice and redundantly recomputes the cheap
// block-local vote from mem0 (8 KB). Fast path (vote passes at t=0, true for
// the benchmark data): 20 closed-form nontemporal float4 row-stores. Slow
// path (general data): faithful block-local recurrence, still correct.

#define T_STEPS   500
#define BATCH     32
#define N_INP     512
#define N_HID     2048
#define THRESH    (-55.0f)
#define BETA_V    0.95f
#define REST      70.0f
#define REFRAC_P  5

#define T_CHUNK   20
#define N_CHUNKS  (T_STEPS / T_CHUNK)   // 25
#define ROW       (BATCH * N_HID)       // 65536 floats per timestep

typedef float vfloat4 __attribute__((ext_vector_type(4)));

__global__ __launch_bounds__(256) void rsnn_fused(
    const float* __restrict__ x,       // [B, T, N_INP]
    const float* __restrict__ mem0,    // [B, N_HID]
    const float* __restrict__ W_in,    // [N_HID, N_INP]
    const float* __restrict__ b_in,    // [N_HID]
    const float* __restrict__ W_rec,   // [N_HID, N_HID]
    const float* __restrict__ b_rec,   // [N_HID]
    float* __restrict__ out)           // [T, B, N_HID]
{
    const int bid  = blockIdx.x;           // 1600 blocks
    const int tg   = bid >> 6;             // time-chunk [0,25)
    const int sub  = bid & 63;
    const int b    = sub >> 1;             // batch [0,32)
    const int half = sub & 1;              // half of hidden row
    const int tid  = threadIdx.x;          // 256 threads

    const int t0   = tg * T_CHUNK;
    const int tEnd = t0 + T_CHUNK;

    __shared__ float spkLDS[N_HID];
    __shared__ int   flag;

    // 8 neurons/thread: group0 = tid*4..+3, group1 = 1024+tid*4..+3.
    // Write columns (half*1024 + tid*4 ..+3) are this thread's group `half`.
    float mem[8];
    int   rr[8]  = {0,0,0,0,0,0,0,0};
    float spk[8] = {0,0,0,0,0,0,0,0};

    {
        const float4 a = *(const float4*)(mem0 + b * N_HID + tid * 4);
        const float4 c = *(const float4*)(mem0 + b * N_HID + 1024 + tid * 4);
        mem[0]=a.x; mem[1]=a.y; mem[2]=a.z; mem[3]=a.w;
        mem[4]=c.x; mem[5]=c.y; mem[6]=c.z; mem[7]=c.w;
    }
    *(float4*)(spkLDS + tid * 4)        = make_float4(0.f, 0.f, 0.f, 0.f);
    *(float4*)(spkLDS + 1024 + tid * 4) = make_float4(0.f, 0.f, 0.f, 0.f);

    int te = tEnd;
    for (int t = 0; t < tEnd; ++t) {
        if (tid == 0) flag = 0;
        __syncthreads();                   // orders prev spkLDS writes too
        bool bad = false;
#pragma unroll
        for (int j = 0; j < 8; ++j) bad |= !(mem[j] > THRESH);
        if (bad) flag = 1;
        __syncthreads();
        if (flag == 0) { te = t; break; }  // block-uniform: absorbed

        // ---- general (slow) step — never executed on benchmark data ----
#pragma unroll
        for (int j = 0; j < 8; ++j) {
            const int h = (j < 4) ? (tid * 4 + j) : (1024 + tid * 4 + (j - 4));
            rr[j] = max(rr[j] - 1, 0);
            const bool reset = (mem[j] > THRESH);
            float m;
            if (!reset) {
                float rec = 0.f;
                const float* wr = W_rec + (size_t)h * N_HID;
                for (int k = 0; k < N_HID; ++k) rec += spkLDS[k] * wr[k];
                float cur = b_in[h];
                const float* xi = x + ((size_t)b * T_STEPS + t) * N_INP;
                const float* wi = W_in + (size_t)h * N_INP;
                for (int k = 0; k < N_INP; ++k) cur += xi[k] * wi[k];
                m = BETA_V * (mem[j] + REST) + cur + rec + b_rec[h] - REST;
            } else {
                m = 0.f;
            }
            mem[j] = m;
            spk[j] = ((m > THRESH) && (rr[j] == 0)) ? 1.f : 0.f;
            if (spk[j] > 0.f) rr[j] = REFRAC_P;
        }
        __syncthreads();                   // finish spkLDS reads before overwrite
#pragma unroll
        for (int j = 0; j < 4; ++j) spkLDS[tid * 4 + j]        = spk[j];
#pragma unroll
        for (int j = 0; j < 4; ++j) spkLDS[1024 + tid * 4 + j] = spk[4 + j];

        if (t >= t0) {                     // write this block's slice of row t
            vfloat4 o;
            o.x = spk[half * 4 + 0];
            o.y = spk[half * 4 + 1];
            o.z = spk[half * 4 + 2];
            o.w = spk[half * 4 + 3];
            __builtin_nontemporal_store(o,
                (vfloat4*)(out + (size_t)t * ROW + b * N_HID + half * 1024 + tid * 4));
        }
        // next iteration's top barrier orders spkLDS writes before reads
    }

    // ---- closed-form tail for t in [max(t0, te), tEnd) ----
    const int r0 = rr[half * 4 + 0], r1 = rr[half * 4 + 1];
    const int r2 = rr[half * 4 + 2], r3 = rr[half * 4 + 3];
    const int s0x = r0 ? r0 - 1 : 0;
    const int s0y = r1 ? r1 - 1 : 0;
    const int s0z = r2 ? r2 - 1 : 0;
    const int s0w = r3 ? r3 - 1 : 0;

    const int tStart = (t0 > te) ? t0 : te;
    int sm = (tStart - te) % 5;
    float* p = out + (size_t)tStart * ROW + b * N_HID + half * 1024 + tid * 4;

    for (int t = tStart; t < tEnd; ++t) {
        vfloat4 o;
        o.x = (sm == s0x) ? 1.f : 0.f;
        o.y = (sm == s0y) ? 1.f : 0.f;
        o.z = (sm == s0z) ? 1.f : 0.f;
        o.w = (sm == s0w) ? 1.f : 0.f;
        __builtin_nontemporal_store(o, (vfloat4*)p);
        sm = (sm == 4) ? 0 : sm + 1;
        p += ROW;
    }
}

extern "C" void kernel_launch(void* const* d_in, const int* in_sizes, int n_in,
                              void* d_out, int out_size, void* d_ws, size_t ws_size,
                              hipStream_t stream) {
    const float* x     = (const float*)d_in[0];
    const float* mem0  = (const float*)d_in[1];
    const float* W_in  = (const float*)d_in[2];
    const float* b_in  = (const float*)d_in[3];
    const float* W_rec = (const float*)d_in[4];
    const float* b_rec = (const float*)d_in[5];
    float* out = (float*)d_out;

    rsnn_fused<<<N_CHUNKS * 64, 256, 0, stream>>>(x, mem0, W_in, b_in,
                                                  W_rec, b_rec, out);
}